// Round 2
// baseline (19437.849 us; speedup 1.0000x reference)
//
#include <hip/hip_runtime.h>
#include <math.h>

#define BATCH 64
#define SEQ   512
#define DIMK  1024
#define HID   1024
#define NWG   256
#define BLK   512
#define HPW   4      // hidden units per workgroup (256 * 4 = 1024)
#define BPAD  1032   // LDS B col stride in bf16 elems (1024 + 8 pad)
#define BH    (BATCH * HID)

typedef short  frag8 __attribute__((ext_vector_type(8)));
typedef float  f4    __attribute__((ext_vector_type(4)));

__device__ __forceinline__ unsigned short f2bf(float f){
    unsigned u = __builtin_bit_cast(unsigned, f);
    u = (u + 0x7fffu + ((u >> 16) & 1u)) >> 16;   // RNE
    return (unsigned short)u;
}
__device__ __forceinline__ float bf2f(unsigned short s){
    unsigned u = ((unsigned)s) << 16;
    return __builtin_bit_cast(float, u);
}

// Stage 16 columns (4 gates x 4 hidden) of four 1024x1024 fp32 matrices into LDS as bf16.
// lo_mode=1 stages the bf16 "low" residual (split precision).
__device__ __forceinline__ void stage_cols(const float* const M[4], int hbase, short* Bl, int lo_mode){
    int kk = threadIdx.x >> 2;   // 0..127
    int c  = threadIdx.x & 3;
    #pragma unroll
    for (int g = 0; g < 4; ++g){
        const float* Mg = M[g];
        #pragma unroll
        for (int k0 = 0; k0 < DIMK; k0 += 128){
            int k = k0 + kk;
            float v = Mg[(long)k * HID + hbase + c];
            unsigned short hi = f2bf(v);
            unsigned short w  = lo_mode ? f2bf(v - bf2f(hi)) : hi;
            Bl[(g*4 + c) * BPAD + k] = (short)w;
        }
    }
}

// One GEMM pass: acc += h_plane(bf16, 64x1024) @ Blds(1024x16). 8 waves: m-split(4) x k-split(2).
__device__ __forceinline__ f4 gemm_h(const unsigned short* h, const short* Bl, f4 acc){
    int lane = threadIdx.x & 63;
    int wave = threadIdx.x >> 6;
    int m  = wave & 3;
    int ks = wave >> 2;
    int row = 16*m + (lane & 15);
    int kb  = ks*512 + ((lane >> 4) * 8);
    const short* Ap = (const short*)h + row * HID + kb;
    const short* Bp = Bl + (lane & 15) * BPAD + kb;
    frag8 a[16], b[16];
    #pragma unroll
    for (int i = 0; i < 16; ++i) a[i] = *(const frag8*)(Ap + i*32);
    #pragma unroll
    for (int i = 0; i < 16; ++i) b[i] = *(const frag8*)(Bp + i*32);
    #pragma unroll
    for (int i = 0; i < 16; ++i)
        acc = __builtin_amdgcn_mfma_f32_16x16x32_bf16(a[i], b[i], acc, 0, 0, 0);
    return acc;
}

// Phase-0 GEMM: acc += split(x0) @ Blds, x fp32 with row stride SEQ*DIMK.
__device__ __forceinline__ f4 gemm_x(const float* x, int lo_mode, const short* Bl, f4 acc){
    int lane = threadIdx.x & 63;
    int wave = threadIdx.x >> 6;
    int m  = wave & 3;
    int ks = wave >> 2;
    int row = 16*m + (lane & 15);
    int kb  = ks*512 + ((lane >> 4) * 8);
    const float* Ar = x + (long)row * (SEQ * DIMK) + kb;
    const short* Bp = Bl + (lane & 15) * BPAD + kb;
    #pragma unroll
    for (int i = 0; i < 16; ++i){
        frag8 af;
        #pragma unroll
        for (int j = 0; j < 8; ++j){
            float v = Ar[i*32 + j];
            unsigned short hi = f2bf(v);
            af[j] = (short)(lo_mode ? f2bf(v - bf2f(hi)) : hi);
        }
        frag8 bv = *(const frag8*)(Bp + i*32);
        acc = __builtin_amdgcn_mfma_f32_16x16x32_bf16(af, bv, acc, 0, 0, 0);
    }
    return acc;
}

// C-frag (col=lane&15, row=(lane>>4)*4+r) -> padded LDS scratch
__device__ __forceinline__ void write_scr(f4 acc, float (*scr)[64][20]){
    int lane = threadIdx.x & 63;
    int wave = threadIdx.x >> 6;
    int m  = wave & 3;
    int ks = wave >> 2;
    int col = lane & 15;
    #pragma unroll
    for (int r = 0; r < 4; ++r){
        int row = 16*m + (lane >> 4)*4 + r;
        scr[ks][row][col] = acc[r];
    }
}

// Grid barrier: monotonic counter, agent-scope fences (cross-XCD safe).
__device__ __forceinline__ void gbar(unsigned* cnt, unsigned target){
    __syncthreads();
    if (threadIdx.x == 0){
        __builtin_amdgcn_fence(__ATOMIC_RELEASE, "agent");
        __hip_atomic_fetch_add(cnt, 1u, __ATOMIC_RELAXED, __HIP_MEMORY_SCOPE_AGENT);
        while (__hip_atomic_load(cnt, __ATOMIC_RELAXED, __HIP_MEMORY_SCOPE_AGENT) < target)
            __builtin_amdgcn_s_sleep(1);
    }
    __syncthreads();
    __builtin_amdgcn_fence(__ATOMIC_ACQUIRE, "agent");
}

__global__ void __launch_bounds__(BLK, 2)
lstm_kernel(const float* x,
            const float* wf, const float* wi, const float* wo, const float* wc,
            const float* uf, const float* ui, const float* uo, const float* uc,
            const float* bfp, const float* bip, const float* bop, const float* bcp,
            float* out, unsigned* cnt, unsigned short* hbuf)
{
    __shared__ short BlH[16 * BPAD];       // U_hi slice (resident after phase 0)
    __shared__ short BlL[16 * BPAD];       // U_lo slice
    __shared__ float scr[2][64][20];       // C-frag exchange scratch

    const int tid   = threadIdx.x;
    const int hbase = blockIdx.x * HPW;

    const float* Ws[4] = {wf, wi, wo, wc};
    const float* Us[4] = {uf, ui, uo, uc};
    const float* Bs[4] = {bfp, bip, bop, bcp};

    // ---- Phase 0: gx = x0 @ W + b in split-bf16 (3 MFMA passes) ----
    f4 acc = {0.f, 0.f, 0.f, 0.f};
    stage_cols(Ws, hbase, BlH, 0);
    stage_cols(Ws, hbase, BlL, 1);
    __syncthreads();
    acc = gemm_x(x, 0, BlH, acc);          // x_hi * W_hi
    acc = gemm_x(x, 1, BlH, acc);          // x_lo * W_hi
    acc = gemm_x(x, 0, BlL, acc);          // x_hi * W_lo
    __syncthreads();
    stage_cols(Us, hbase, BlH, 0);         // U_hi resident for the whole recurrence
    stage_cols(Us, hbase, BlL, 1);         // U_lo resident
    write_scr(acc, scr);
    __syncthreads();

    float gx0 = 0.f, gx1 = 0.f, gx2 = 0.f, gx3 = 0.f, cstate = 0.f;
    const int b  = tid >> 2;
    const int cc = tid & 3;
    if (tid < 256){
        gx0 = scr[0][b][ 0 + cc] + scr[1][b][ 0 + cc] + Bs[0][hbase + cc];
        gx1 = scr[0][b][ 4 + cc] + scr[1][b][ 4 + cc] + Bs[1][hbase + cc];
        gx2 = scr[0][b][ 8 + cc] + scr[1][b][ 8 + cc] + Bs[2][hbase + cc];
        gx3 = scr[0][b][12 + cc] + scr[1][b][12 + cc] + Bs[3][hbase + cc];
    }
    __syncthreads();   // scr reads done before t=0 overwrites it

    // ---- Recurrence: 512 steps, 1 grid barrier each, ping-pong split-bf16 h ----
    for (int t = 0; t < SEQ; ++t){
        // hbuf layout: [pingpong][plane hi/lo][BATCH*HID]
        const unsigned short* hcH = hbuf + (t & 1) * (2 * BH);
        const unsigned short* hcL = hcH + BH;
        unsigned short*       hnH = hbuf + ((t + 1) & 1) * (2 * BH);
        unsigned short*       hnL = hnH + BH;

        f4 z = {0.f, 0.f, 0.f, 0.f};
        z = gemm_h(hcH, BlH, z);           // h_hi @ U_hi
        z = gemm_h(hcL, BlH, z);           // h_lo @ U_hi
        z = gemm_h(hcH, BlL, z);           // h_hi @ U_lo
        write_scr(z, scr);
        __syncthreads();

        if (tid < 256){
            float zf = gx0 + scr[0][b][ 0 + cc] + scr[1][b][ 0 + cc];
            float zi = gx1 + scr[0][b][ 4 + cc] + scr[1][b][ 4 + cc];
            float zo = gx2 + scr[0][b][ 8 + cc] + scr[1][b][ 8 + cc];
            float zc = gx3 + scr[0][b][12 + cc] + scr[1][b][12 + cc];
            float f  = 1.0f / (1.0f + expf(-zf));
            float ii = 1.0f / (1.0f + expf(-zi));
            float o  = 1.0f / (1.0f + expf(-zo));
            float ch = tanhf(zc);
            cstate   = f * cstate + ii * ch;
            float hv = o * tanhf(cstate);
            unsigned short hhi = f2bf(hv);
            unsigned short hlo = f2bf(hv - bf2f(hhi));
            hnH[b * HID + hbase + cc] = hhi;
            hnL[b * HID + hbase + cc] = hlo;
            out[(long)b * (SEQ * HID) + (long)t * HID + hbase + cc] = hv;
        }
        if (t < SEQ - 1)
            gbar(cnt, (unsigned)(t + 1) * NWG);
    }
}

extern "C" void kernel_launch(void* const* d_in, const int* in_sizes, int n_in,
                              void* d_out, int out_size, void* d_ws, size_t ws_size,
                              hipStream_t stream)
{
    const float* x  = (const float*)d_in[0];
    const float* wf = (const float*)d_in[1];
    const float* wi = (const float*)d_in[2];
    const float* wo = (const float*)d_in[3];
    const float* wc = (const float*)d_in[4];
    const float* uf = (const float*)d_in[5];
    const float* ui = (const float*)d_in[6];
    const float* uo = (const float*)d_in[7];
    const float* uc = (const float*)d_in[8];
    const float* bf = (const float*)d_in[9];
    const float* bi = (const float*)d_in[10];
    const float* bo = (const float*)d_in[11];
    const float* bc = (const float*)d_in[12];
    float* out = (float*)d_out;

    unsigned*       cnt  = (unsigned*)d_ws;
    unsigned short* hbuf = (unsigned short*)((char*)d_ws + 256);

    // zero barrier counter + both h ping-pong buffers, both hi/lo planes (h0 = 0)
    hipMemsetAsync(d_ws, 0, 256 + 2 * 2 * BH * sizeof(unsigned short), stream);

    void* args[] = { &x, &wf, &wi, &wo, &wc, &uf, &ui, &uo, &uc,
                     &bf, &bi, &bo, &bc, &out, &cnt, &hbuf };
    hipLaunchCooperativeKernel((void*)lstm_kernel, dim3(NWG), dim3(BLK), args, 0, stream);
}

// Round 3
// 9371.168 us; speedup vs baseline: 2.0742x; 2.0742x over previous
//
#include <hip/hip_runtime.h>
#include <math.h>

#define BATCH 64
#define SEQ   512
#define DIMK  1024
#define HID   1024
#define NWG   128
#define BLK   512
#define HPW   8           // hidden columns per WG
#define NCOL  32          // 4 gates * HPW
#define BPAD  1032        // LDS col stride (1024 + 8)
#define BH    (BATCH * HID)

typedef _Float16 h8  __attribute__((ext_vector_type(8)));
typedef float    f4  __attribute__((ext_vector_type(4)));
typedef float    fv4 __attribute__((ext_vector_type(4)));
typedef unsigned long long u64;

#define MFMA(a, b, c) __builtin_amdgcn_mfma_f32_16x16x32_f16(a, b, c, 0, 0, 0)

// 16-B fragment load, LLC-coherent (sc0 sc1), bypasses L1/L2 — no fences needed.
__device__ __forceinline__ h8 ldh8_llc(const _Float16* p){
    union { u64 q[2]; h8 v; } r;
    const u64* q = (const u64*)p;
    r.q[0] = __hip_atomic_load((u64*)(q + 0), __ATOMIC_RELAXED, __HIP_MEMORY_SCOPE_AGENT);
    r.q[1] = __hip_atomic_load((u64*)(q + 1), __ATOMIC_RELAXED, __HIP_MEMORY_SCOPE_AGENT);
    return r.v;
}

// Stage 32 columns (4 gates x 8 hidden) of four fp32 matrices into LDS as fp16 hi+lo planes.
__device__ __forceinline__ void stage32(const float* const M[4], int hb,
                                        _Float16* BlH, _Float16* BlL){
    int jj = threadIdx.x & 7;
    int kk = threadIdx.x >> 3;          // 0..63
    #pragma unroll
    for (int g = 0; g < 4; ++g){
        const float* Mg = M[g];
        #pragma unroll
        for (int it = 0; it < 16; ++it){
            int k = kk + 64 * it;
            float v = Mg[(long)k * HID + hb + jj];
            _Float16 hi = (_Float16)v;
            _Float16 lo = (_Float16)(v - (float)hi);
            BlH[(g * HPW + jj) * BPAD + k] = hi;
            BlL[(g * HPW + jj) * BPAD + k] = lo;
        }
    }
}

__global__ void __launch_bounds__(BLK, 2)
lstm_kernel(const float* x,
            const float* wf, const float* wi, const float* wo, const float* wc,
            const float* uf, const float* ui, const float* uo, const float* uc,
            const float* bfp, const float* bip, const float* bop, const float* bcp,
            float* out, unsigned* cnt, _Float16* hbuf)
{
    __shared__ _Float16 BlH[NCOL * BPAD];          // U_hi (fp16), resident after phase 0
    __shared__ _Float16 BlL[NCOL * BPAD];          // U_lo residual
    __shared__ float    scr[2][64][NCOL + 4];      // k-split reduction / exchange
    __shared__ unsigned short hx[2][64][HPW];      // h pack staging (hi/lo planes)

    const int tid  = threadIdx.x;
    const int lane = tid & 63;
    const int wave = tid >> 6;
    const int mt   = wave & 3;          // m-tile (16 rows of batch)
    const int ks   = wave >> 2;         // k-half (512)
    const int hb   = blockIdx.x * HPW;

    const int arow = mt * 16 + (lane & 15);
    const int kb   = ks * 512 + ((lane >> 4) * 8);
    const int bcol = lane & 15;

    const float* Ws[4] = {wf, wi, wo, wc};
    const float* Us[4] = {uf, ui, uo, uc};

    // ---- Phase 0: gx = x0 @ W + b, fp16 split (x_hi/x_lo, W_hi/W_lo) ----
    stage32(Ws, hb, BlH, BlL);
    __syncthreads();

    f4 acc0 = {0.f,0.f,0.f,0.f}, acc1 = {0.f,0.f,0.f,0.f};
    {
        const float* Ar = x + (long)arow * (SEQ * DIMK);
        #pragma unroll 4
        for (int i = 0; i < 16; ++i){
            int k = kb + i * 32;
            fv4 xa = *(const fv4*)(Ar + k);
            fv4 xb = *(const fv4*)(Ar + k + 4);
            h8 xhi, xlo;
            #pragma unroll
            for (int j = 0; j < 4; ++j){
                xhi[j]   = (_Float16)xa[j];  xlo[j]   = (_Float16)(xa[j] - (float)xhi[j]);
                xhi[4+j] = (_Float16)xb[j];  xlo[4+j] = (_Float16)(xb[j] - (float)xhi[4+j]);
            }
            h8 b0h = *(const h8*)&BlH[ bcol       * BPAD + k];
            h8 b1h = *(const h8*)&BlH[(16 + bcol) * BPAD + k];
            h8 b0l = *(const h8*)&BlL[ bcol       * BPAD + k];
            h8 b1l = *(const h8*)&BlL[(16 + bcol) * BPAD + k];
            acc0 = MFMA(xhi, b0h, acc0); acc0 = MFMA(xlo, b0h, acc0); acc0 = MFMA(xhi, b0l, acc0);
            acc1 = MFMA(xhi, b1h, acc1); acc1 = MFMA(xlo, b1h, acc1); acc1 = MFMA(xhi, b1l, acc1);
        }
    }
    {
        int r0 = mt * 16 + ((lane >> 4) << 2);
        #pragma unroll
        for (int r = 0; r < 4; ++r){
            scr[ks][r0 + r][bcol]      = acc0[r];
            scr[ks][r0 + r][16 + bcol] = acc1[r];
        }
    }
    __syncthreads();

    const int eb = tid >> 3;            // batch row this thread owns
    const int ej = tid & 7;             // hidden col within WG slice
    float gx0 = scr[0][eb][ 0 + ej] + scr[1][eb][ 0 + ej] + bfp[hb + ej];
    float gx1 = scr[0][eb][ 8 + ej] + scr[1][eb][ 8 + ej] + bip[hb + ej];
    float gx2 = scr[0][eb][16 + ej] + scr[1][eb][16 + ej] + bop[hb + ej];
    float gx3 = scr[0][eb][24 + ej] + scr[1][eb][24 + ej] + bcp[hb + ej];
    stage32(Us, hb, BlH, BlL);          // U resident for the whole recurrence
    __syncthreads();

    // ---- Recurrence: 512 steps, LLC-coherent h exchange, no cache-maintenance ops ----
    float cstate = 0.f;
    const long obase = (long)eb * (SEQ * HID) + hb + ej;

    for (int t = 0; t < SEQ; ++t){
        const _Float16* hcH = hbuf + (t & 1) * (2 * BH);
        const _Float16* hcL = hcH + BH;
        _Float16* hnH = hbuf + ((t + 1) & 1) * (2 * BH);
        _Float16* hnL = hnH + BH;

        // A fragments: load once (hi & lo), reuse across U_hi and U_lo passes.
        h8 aH[16], aL[16];
        const _Float16* ApH = hcH + arow * HID + kb;
        const _Float16* ApL = hcL + arow * HID + kb;
        #pragma unroll
        for (int i = 0; i < 16; ++i) aH[i] = ldh8_llc(ApH + i * 32);
        #pragma unroll
        for (int i = 0; i < 16; ++i) aL[i] = ldh8_llc(ApL + i * 32);

        f4 z0 = {0.f,0.f,0.f,0.f}, z1 = {0.f,0.f,0.f,0.f};
        #pragma unroll
        for (int i = 0; i < 16; ++i){
            int k = kb + i * 32;
            h8 b0h = *(const h8*)&BlH[ bcol       * BPAD + k];
            h8 b1h = *(const h8*)&BlH[(16 + bcol) * BPAD + k];
            h8 b0l = *(const h8*)&BlL[ bcol       * BPAD + k];
            h8 b1l = *(const h8*)&BlL[(16 + bcol) * BPAD + k];
            z0 = MFMA(aH[i], b0h, z0); z0 = MFMA(aL[i], b0h, z0); z0 = MFMA(aH[i], b0l, z0);
            z1 = MFMA(aH[i], b1h, z1); z1 = MFMA(aL[i], b1h, z1); z1 = MFMA(aH[i], b1l, z1);
        }
        {
            int r0 = mt * 16 + ((lane >> 4) << 2);
            #pragma unroll
            for (int r = 0; r < 4; ++r){
                scr[ks][r0 + r][bcol]      = z0[r];
                scr[ks][r0 + r][16 + bcol] = z1[r];
            }
        }
        __syncthreads();

        float zf = gx0 + scr[0][eb][ 0 + ej] + scr[1][eb][ 0 + ej];
        float zi = gx1 + scr[0][eb][ 8 + ej] + scr[1][eb][ 8 + ej];
        float zo = gx2 + scr[0][eb][16 + ej] + scr[1][eb][16 + ej];
        float zc = gx3 + scr[0][eb][24 + ej] + scr[1][eb][24 + ej];
        float f  = 1.0f / (1.0f + expf(-zf));
        float ii = 1.0f / (1.0f + expf(-zi));
        float o  = 1.0f / (1.0f + expf(-zo));
        float ch = tanhf(zc);
        cstate   = f * cstate + ii * ch;
        float hv = o * tanhf(cstate);
        out[obase + (long)t * HID] = hv;

        _Float16 hhi = (_Float16)hv;
        _Float16 hlo = (_Float16)(hv - (float)hhi);
        hx[0][eb][ej] = __builtin_bit_cast(unsigned short, hhi);
        hx[1][eb][ej] = __builtin_bit_cast(unsigned short, hlo);
        __syncthreads();                 // hx complete; also protects scr for next step

        // Packed LLC-coherent h store: 512 threads cover 2 planes x 64 b x 4 dwords.
        {
            int p = tid >> 8, rr = tid & 255, b = rr >> 2, w = rr & 3;
            unsigned v = (unsigned)hx[p][b][2*w] | ((unsigned)hx[p][b][2*w + 1] << 16);
            unsigned* dst = (unsigned*)(p ? hnL : hnH) + b * (HID / 2) + (hb >> 1) + w;
            __hip_atomic_store(dst, v, __ATOMIC_RELAXED, __HIP_MEMORY_SCOPE_AGENT);
        }

        if (t < SEQ - 1){
            __syncthreads();             // drains every wave's vmcnt before arrive
            if (tid == 0){
                __hip_atomic_fetch_add(cnt, 1u, __ATOMIC_RELAXED, __HIP_MEMORY_SCOPE_AGENT);
                unsigned tgt = (unsigned)(t + 1) * NWG;
                while (__hip_atomic_load(cnt, __ATOMIC_RELAXED, __HIP_MEMORY_SCOPE_AGENT) < tgt)
                    __builtin_amdgcn_s_sleep(1);
            }
            __syncthreads();
        }
    }
}

extern "C" void kernel_launch(void* const* d_in, const int* in_sizes, int n_in,
                              void* d_out, int out_size, void* d_ws, size_t ws_size,
                              hipStream_t stream)
{
    const float* x  = (const float*)d_in[0];
    const float* wf = (const float*)d_in[1];
    const float* wi = (const float*)d_in[2];
    const float* wo = (const float*)d_in[3];
    const float* wc = (const float*)d_in[4];
    const float* uf = (const float*)d_in[5];
    const float* ui = (const float*)d_in[6];
    const float* uo = (const float*)d_in[7];
    const float* uc = (const float*)d_in[8];
    const float* bf = (const float*)d_in[9];
    const float* bi = (const float*)d_in[10];
    const float* bo = (const float*)d_in[11];
    const float* bc = (const float*)d_in[12];
    float* out = (float*)d_out;

    unsigned*  cnt  = (unsigned*)d_ws;
    _Float16*  hbuf = (_Float16*)((char*)d_ws + 256);

    // zero barrier counter + both h ping-pong buffers (hi+lo planes); h0 = 0
    hipMemsetAsync(d_ws, 0, 256 + (size_t)2 * 2 * BH * sizeof(_Float16), stream);

    void* args[] = { &x, &wf, &wi, &wo, &wc, &uf, &ui, &uo, &uc,
                     &bf, &bi, &bo, &bc, &out, &cnt, &hbuf };
    hipLaunchCooperativeKernel((void*)lstm_kernel, dim3(NWG), dim3(BLK), args, 0, stream);
}